// Round 18
// baseline (1028.429 us; speedup 1.0000x reference)
//
#include <hip/hip_runtime.h>
#include <hip/hip_bf16.h>
#include <math.h>

#define B 8
#define N 4096
#define D 256
#define H 8
#define DH 32
#define M 256
#define DEPTH 4
#define HID 1024
#define NRM 0.4204482076268573f   // 32^-0.25

typedef __attribute__((ext_vector_type(8))) short short8;
typedef __attribute__((ext_vector_type(4))) float f32x4;

static __device__ __forceinline__ unsigned short f2bf(float f) {
    __hip_bfloat16 h = __float2bfloat16(f);
    return __builtin_bit_cast(unsigned short, h);
}
static __device__ __forceinline__ float bfu2f(unsigned short u) {
    unsigned int x = ((unsigned int)u) << 16;
    return __builtin_bit_cast(float, x);
}
static __device__ __forceinline__ float gelu_fast(float x) {
    float z = 0.7978845608028654f * (x + 0.044715f * x * x * x);
    float e = __expf(2.0f * z);
    float th = 1.0f - 2.0f / (e + 1.0f);
    return 0.5f * x * (1.0f + th);
}

// ---------------- h = x + pos ----------------
__global__ void add_pos_kernel(const float* __restrict__ x, const float* __restrict__ pos,
                               float* __restrict__ h) {
    int i = blockIdx.x * 256 + threadIdx.x;
    int nd = i % (N * D);
    h[i] = x[i] + pos[nd];
}

// ---------------- proj fp32 -> bf16 copy ----------------
__global__ void projbf_kernel(const float* __restrict__ in, unsigned short* __restrict__ out) {
    int i = blockIdx.x * 256 + threadIdx.x;     // DEPTH*M*DH elements
    out[i] = f2bf(in[i]);
}

// ---- weight fp32 (K x N) -> bf16 transposed (N x K), cols < slim scaled by NRM ----
__global__ __launch_bounds__(256) void wtrans_kernel(const float* __restrict__ in,
                                                     unsigned short* __restrict__ out,
                                                     int Kd, int Nd, int slim) {
    __shared__ float tl[32][33];
    int n0 = blockIdx.x * 32, k0 = blockIdx.y * 32;
    int t = threadIdx.x;
    int kk = t >> 3, c4 = (t & 7) * 4;
    float4 v = *reinterpret_cast<const float4*>(&in[(size_t)(k0 + kk) * Nd + n0 + c4]);
    tl[kk][c4 + 0] = v.x; tl[kk][c4 + 1] = v.y; tl[kk][c4 + 2] = v.z; tl[kk][c4 + 3] = v.w;
    __syncthreads();
    int nn = t >> 3, k4 = (t & 7) * 4;
    float sc = (n0 + nn < slim) ? NRM : 1.0f;
    ushort4 o;
    o.x = f2bf(tl[k4 + 0][nn] * sc); o.y = f2bf(tl[k4 + 1][nn] * sc);
    o.z = f2bf(tl[k4 + 2][nn] * sc); o.w = f2bf(tl[k4 + 3][nn] * sc);
    *reinterpret_cast<ushort4*>(&out[(size_t)(n0 + nn) * Kd + k0 + k4]) = o;
}

// ---------------- LayerNorm -> bf16 ----------------
__global__ __launch_bounds__(256) void ln_kernel(const float* __restrict__ in,
                                                 const float* __restrict__ g,
                                                 const float* __restrict__ bb,
                                                 unsigned short* __restrict__ out) {
    int wave = threadIdx.x >> 6, lane = threadIdx.x & 63;
    long row = (long)blockIdx.x * 4 + wave;
    float4 v = reinterpret_cast<const float4*>(in + row * D)[lane];
    float s = v.x + v.y + v.z + v.w;
#pragma unroll
    for (int o = 32; o >= 1; o >>= 1) s += __shfl_xor(s, o);
    float mu = s * (1.0f / D);
    float d0 = v.x - mu, d1 = v.y - mu, d2 = v.z - mu, d3 = v.w - mu;
    float ss = d0 * d0 + d1 * d1 + d2 * d2 + d3 * d3;
#pragma unroll
    for (int o = 32; o >= 1; o >>= 1) ss += __shfl_xor(ss, o);
    float inv = rsqrtf(ss * (1.0f / D) + 1e-6f);
    float4 gv = reinterpret_cast<const float4*>(g)[lane];
    float4 bv = reinterpret_cast<const float4*>(bb)[lane];
    ushort4 o4;
    o4.x = f2bf(d0 * inv * gv.x + bv.x);
    o4.y = f2bf(d1 * inv * gv.y + bv.y);
    o4.z = f2bf(d2 * inv * gv.z + bv.z);
    o4.w = f2bf(d3 * inv * gv.w + bv.w);
    *reinterpret_cast<ushort4*>(&out[row * D + lane * 4]) = o4;
}

// ---------------- bf16 MFMA GEMM: out = A(MxK) @ Bt(NxK)^T ----------------
// Block 256x128, BK=32, 4 waves as 2x2, wave tile 128x64 (acc[8][4]).
// Double-buffered reg-staged LDS, ONE barrier per K-step, chunk-XOR swizzle
// (conflict-free write+read), XCD-swizzled grid, operand-swapped MFMA.
template <bool BIAS, bool GELU_ACT, bool RESID, bool OUT16>
__global__ __launch_bounds__(256) void mgemm_kernel(const unsigned short* __restrict__ A,
                                                    const unsigned short* __restrict__ Bt,
                                                    const float* __restrict__ bias,
                                                    float* __restrict__ C,
                                                    unsigned short* __restrict__ O16,
                                                    int K, int Nc) {
    __shared__ __align__(16) short Als[2][256][32];   // 32 KB
    __shared__ __align__(16) short Bls[2][128][32];   // 16 KB
    int t = threadIdx.x;
    int l = t & 63, w = t >> 6;
    int wr = w >> 1, wc = w & 1;
    int nwg = gridDim.x * gridDim.y;
    int bid = blockIdx.y * gridDim.x + blockIdx.x;
    int lgid = (bid & 7) * (nwg >> 3) + (bid >> 3);
    int bx = lgid % gridDim.x;
    int by = lgid / gridDim.x;
    long m0 = (long)by * 256;
    int n0 = bx * 128;
    int lr = l & 15, lg = l >> 4;

    // staging sources: A row t (4 chunks), B row t>>1 half t&1 (2 chunks)
    const unsigned short* Ap = &A[(size_t)(m0 + t) * K];
    int brow = t >> 1, bhalf = t & 1;
    const unsigned short* Bp = &Bt[(size_t)(n0 + brow) * K + bhalf * 16];
    int asw = (t >> 1) & 3;          // A write swizzle key (row = t)
    int bsw = (brow >> 1) & 3;       // B write swizzle key
    int cr = (lg ^ ((lr >> 1) & 3)) * 8;   // frag read column (matches write swz)

    short8 ra[4], rb[2];
    // ---- prologue: tile0 -> buf0 ----
#pragma unroll
    for (int i = 0; i < 4; i++) ra[i] = *reinterpret_cast<const short8*>(Ap + i * 8);
#pragma unroll
    for (int s = 0; s < 2; s++) rb[s] = *reinterpret_cast<const short8*>(Bp + s * 8);
#pragma unroll
    for (int i = 0; i < 4; i++)
        *reinterpret_cast<short8*>(&Als[0][t][((i ^ asw) * 8)]) = ra[i];
#pragma unroll
    for (int s = 0; s < 2; s++)
        *reinterpret_cast<short8*>(&Bls[0][brow][(((bhalf * 2 + s) ^ bsw) * 8)]) = rb[s];
    int nk = K >> 5;
    if (nk > 1) {
#pragma unroll
        for (int i = 0; i < 4; i++) ra[i] = *reinterpret_cast<const short8*>(Ap + 32 + i * 8);
#pragma unroll
        for (int s = 0; s < 2; s++) rb[s] = *reinterpret_cast<const short8*>(Bp + 32 + s * 8);
    }
    __syncthreads();

    f32x4 acc[8][4];
#pragma unroll
    for (int i = 0; i < 8; i++)
#pragma unroll
        for (int j = 0; j < 4; j++) acc[i][j] = (f32x4){0.f, 0.f, 0.f, 0.f};

#pragma unroll 2
    for (int it = 0; it < nk; it++) {
        int buf = it & 1;
        short8 a[8], b[4];
#pragma unroll
        for (int i = 0; i < 8; i++)
            a[i] = *reinterpret_cast<const short8*>(&Als[buf][wr * 128 + i * 16 + lr][cr]);
#pragma unroll
        for (int j = 0; j < 4; j++)
            b[j] = *reinterpret_cast<const short8*>(&Bls[buf][wc * 64 + j * 16 + lr][cr]);
        if (it + 1 < nk) {
            int nb = buf ^ 1;
#pragma unroll
            for (int i = 0; i < 4; i++)
                *reinterpret_cast<short8*>(&Als[nb][t][((i ^ asw) * 8)]) = ra[i];
#pragma unroll
            for (int s = 0; s < 2; s++)
                *reinterpret_cast<short8*>(&Bls[nb][brow][(((bhalf * 2 + s) ^ bsw) * 8)]) = rb[s];
            if (it + 2 < nk) {
                int ko = (it + 2) * 32;
#pragma unroll
                for (int i = 0; i < 4; i++)
                    ra[i] = *reinterpret_cast<const short8*>(Ap + ko + i * 8);
#pragma unroll
                for (int s = 0; s < 2; s++)
                    rb[s] = *reinterpret_cast<const short8*>(Bp + ko + s * 8);
            }
        }
#pragma unroll
        for (int i = 0; i < 8; i++)
#pragma unroll
            for (int j = 0; j < 4; j++)   // swapped: reg-dim = n
                acc[i][j] = __builtin_amdgcn_mfma_f32_16x16x32_bf16(b[j], a[i], acc[i][j], 0, 0, 0);
        __syncthreads();
    }

    float4 bias4[4];
    if (BIAS) {
#pragma unroll
        for (int j = 0; j < 4; j++)
            bias4[j] = *reinterpret_cast<const float4*>(&bias[n0 + wc * 64 + j * 16 + lg * 4]);
    }
#pragma unroll
    for (int i = 0; i < 8; i++) {
        long grow = m0 + wr * 128 + i * 16 + lr;
#pragma unroll
        for (int j = 0; j < 4; j++) {
            int gcol = n0 + wc * 64 + j * 16 + lg * 4;
            f32x4 v = acc[i][j];
            if (BIAS) {
                v[0] += bias4[j].x; v[1] += bias4[j].y; v[2] += bias4[j].z; v[3] += bias4[j].w;
            }
            if (GELU_ACT) {
#pragma unroll
                for (int r = 0; r < 4; r++) v[r] = gelu_fast(v[r]);
            }
            if (OUT16) {
                short4 o;
                o.x = (short)f2bf(v[0]); o.y = (short)f2bf(v[1]);
                o.z = (short)f2bf(v[2]); o.w = (short)f2bf(v[3]);
                *reinterpret_cast<short4*>(&O16[grow * Nc + gcol]) = o;
            } else if (RESID) {
                float4 c0 = *reinterpret_cast<const float4*>(&C[grow * Nc + gcol]);
                c0.x += v[0]; c0.y += v[1]; c0.z += v[2]; c0.w += v[3];
                *reinterpret_cast<float4*>(&C[grow * Nc + gcol]) = c0;
            } else {
                float4 c0 = {v[0], v[1], v[2], v[3]};
                *reinterpret_cast<float4*>(&C[grow * Nc + gcol]) = c0;
            }
        }
    }
}

// ---------------- kv: unshifted exp accumulation, partials [d][m] ----------------
#define KV_P 16
#define KV_ROWS (N / KV_P)      // 256
#define PSZ 8484                // 8192 acc[d][m] + 256 asum + 32 vsum + 1 Lm + pad
__global__ __launch_bounds__(256) void kv_kernel(const unsigned short* __restrict__ qkv16,
                                                 const unsigned short* __restrict__ projbf,
                                                 float* __restrict__ kvp) {
    __shared__ __align__(16) unsigned short kp_s[256][64];    // 32 KB, XOR-swz
    __shared__ __align__(16) unsigned short vT_s[32][66];
    __shared__ float red[4];
    __shared__ float asumred[4][256];
    __shared__ float vred[256][4];
    int t = threadIdx.x;
    int l = t & 63, w = t >> 6;
    int lr = l & 15, lg = l >> 4;
    int bh = blockIdx.x, b = bh >> 3, h = bh & 7;
    int n0 = blockIdx.y * KV_ROWS;
    int rsw = (lr & 7) << 3;

    f32x4 kvacc[4][2];
#pragma unroll
    for (int mf = 0; mf < 4; mf++)
#pragma unroll
        for (int dd = 0; dd < 2; dd++) kvacc[mf][dd] = (f32x4){0.f, 0.f, 0.f, 0.f};
    float asum_p[16];
#pragma unroll
    for (int f = 0; f < 16; f++) asum_p[f] = 0.f;
    float4 vs4 = {0.f, 0.f, 0.f, 0.f};
    float cmax = -1e30f;

    for (int c = 0; c < KV_ROWS / 64; c++) {
        __syncthreads();
        size_t kbase = ((size_t)(b * N) + n0 + c * 64 + w * 16 + lr) * 768 + 256 + h * 32 + lg * 8;
        short8 aq = *reinterpret_cast<const short8*>(qkv16 + kbase);
        float sq = 0.f;
#pragma unroll
        for (int e = 0; e < 8; e++) {
            float xx = bfu2f((unsigned short)aq[e]);
            sq += xx * xx;
        }
        sq += __shfl_xor(sq, 16);
        sq += __shfl_xor(sq, 32);
        float dgr[4];
#pragma unroll
        for (int r = 0; r < 4; r++) dgr[r] = 0.5f * __shfl(sq, lg * 4 + r);
        int cbase = (w * 16 + lg * 4) ^ rsw;
#pragma unroll
        for (int f = 0; f < 16; f++) {
            short8 bq = *reinterpret_cast<const short8*>(projbf + (f * 16 + lr) * 32 + lg * 8);
            f32x4 u = __builtin_amdgcn_mfma_f32_16x16x32_bf16(aq, bq, (f32x4){0.f, 0.f, 0.f, 0.f}, 0, 0, 0);
            cmax = fmaxf(cmax, fmaxf(fmaxf(u[0], u[1]), fmaxf(u[2], u[3])));
            float p0 = __expf(u[0] - dgr[0]);
            float p1 = __expf(u[1] - dgr[1]);
            float p2 = __expf(u[2] - dgr[2]);
            float p3 = __expf(u[3] - dgr[3]);
            asum_p[f] += p0 + p1 + p2 + p3;
            short4 o;
            o.x = (short)f2bf(p0); o.y = (short)f2bf(p1);
            o.z = (short)f2bf(p2); o.w = (short)f2bf(p3);
            *reinterpret_cast<short4*>(&kp_s[f * 16 + lr][cbase]) = o;
        }
#pragma unroll
        for (int ii = 0; ii < 2; ii++) {
            int idx = t + ii * 256;
            int nn = idx >> 3, dz = (idx & 7) * 4;
            const unsigned short* vp =
                qkv16 + ((size_t)(b * N) + n0 + c * 64 + nn) * 768 + 512 + h * 32 + dz;
            short4 vv = *reinterpret_cast<const short4*>(vp);
            float v0 = bfu2f((unsigned short)vv.x), v1 = bfu2f((unsigned short)vv.y);
            float v2 = bfu2f((unsigned short)vv.z), v3 = bfu2f((unsigned short)vv.w);
            vs4.x += v0; vs4.y += v1; vs4.z += v2; vs4.w += v3;
            vT_s[dz + 0][nn] = (unsigned short)vv.x; vT_s[dz + 1][nn] = (unsigned short)vv.y;
            vT_s[dz + 2][nn] = (unsigned short)vv.z; vT_s[dz + 3][nn] = (unsigned short)vv.w;
        }
        __syncthreads();
#pragma unroll
        for (int ks = 0; ks < 2; ks++) {
            short8 bv0 = *reinterpret_cast<const short8*>(&vT_s[lr][ks * 32 + lg * 8]);
            short8 bv1 = *reinterpret_cast<const short8*>(&vT_s[16 + lr][ks * 32 + lg * 8]);
#pragma unroll
            for (int mf = 0; mf < 4; mf++) {
                short8 am = *reinterpret_cast<const short8*>(
                    &kp_s[w * 64 + mf * 16 + lr][(ks * 32 + lg * 8) ^ rsw]);
                kvacc[mf][0] = __builtin_amdgcn_mfma_f32_16x16x32_bf16(am, bv0, kvacc[mf][0], 0, 0, 0);
                kvacc[mf][1] = __builtin_amdgcn_mfma_f32_16x16x32_bf16(am, bv1, kvacc[mf][1], 0, 0, 0);
            }
        }
    }
#pragma unroll
    for (int f = 0; f < 16; f++) {
        asum_p[f] += __shfl_xor(asum_p[f], 16);
        asum_p[f] += __shfl_xor(asum_p[f], 32);
    }
    if (l < 16) {
#pragma unroll
        for (int f = 0; f < 16; f++) asumred[w][f * 16 + l] = asum_p[f];
    }
    vred[t][0] = vs4.x; vred[t][1] = vs4.y; vred[t][2] = vs4.z; vred[t][3] = vs4.w;
#pragma unroll
    for (int o = 1; o < 64; o <<= 1) cmax = fmaxf(cmax, __shfl_xor(cmax, o));
    if (l == 0) red[w] = cmax;
    __syncthreads();
    size_t base = ((size_t)bh * KV_P + blockIdx.y) * PSZ;
#pragma unroll
    for (int mf = 0; mf < 4; mf++)
#pragma unroll
        for (int dd = 0; dd < 2; dd++) {
            int m = w * 64 + mf * 16 + lg * 4;
            int d = dd * 16 + lr;
            float4 o;
            o.x = kvacc[mf][dd][0]; o.y = kvacc[mf][dd][1];
            o.z = kvacc[mf][dd][2]; o.w = kvacc[mf][dd][3];
            *reinterpret_cast<float4*>(&kvp[base + (size_t)d * 256 + m]) = o;
        }
    {
        float s = asumred[0][t] + asumred[1][t] + asumred[2][t] + asumred[3][t];
        kvp[base + 8192 + t] = s;
    }
    if (t < 32) {
        int f4g = t >> 2, cc = t & 3;
        float s = 0.f;
#pragma unroll
        for (int g = 0; g < 32; g++) s += vred[g * 8 + f4g][cc];
        kvp[base + 8448 + t] = s;
    }
    if (t == 0) kvp[base + 8480] = fmaxf(fmaxf(red[0], red[1]), fmaxf(red[2], red[3]));
}

// ---------------- combine partials -> kvT bf16, ksum (grid B*H*4) ----------------
__global__ __launch_bounds__(256) void kv_combine_kernel(const float* __restrict__ kvp,
                                                         unsigned short* __restrict__ kvTb,
                                                         float* __restrict__ ksumf) {
    __shared__ float vst[32];
    int t = threadIdx.x;
    int bh = blockIdx.x >> 2, dq = blockIdx.x & 3;
    size_t base0 = (size_t)bh * KV_P * PSZ;
    float gm = -1e30f;
#pragma unroll
    for (int p = 0; p < KV_P; p++) gm = fmaxf(gm, kvp[base0 + p * PSZ + 8480]);
    if (t < 32) {
        float s = 0.f;
#pragma unroll
        for (int p = 0; p < KV_P; p++) s += kvp[base0 + p * PSZ + 8448 + t];
        vst[t] = s;
    }
    __syncthreads();
    float es = __expf(-gm);
    int d = dq * 8 + (t >> 5);
    int m0 = (t & 31) * 8;
    float4 a0 = {0.f, 0.f, 0.f, 0.f}, a1 = {0.f, 0.f, 0.f, 0.f};
#pragma unroll
    for (int p = 0; p < KV_P; p++) {
        const float* src = &kvp[base0 + p * PSZ + (size_t)d * 256 + m0];
        float4 x0 = *reinterpret_cast<const float4*>(src);
        float4 x1 = *reinterpret_cast<const float4*>(src + 4);
        a0.x += x0.x; a0.y += x0.y; a0.z += x0.z; a0.w += x0.w;
        a1.x += x1.x; a1.y += x1.y; a1.z += x1.z; a1.w += x1.w;
    }
    float vadd = 1e-4f * vst[d];
    ushort4 o0, o1;
    o0.x = f2bf((a0.x * es + vadd) * 0.0625f); o0.y = f2bf((a0.y * es + vadd) * 0.0625f);
    o0.z = f2bf((a0.z * es + vadd) * 0.0625f); o0.w = f2bf((a0.w * es + vadd) * 0.0625f);
    o1.x = f2bf((a1.x * es + vadd) * 0.0625f); o1.y = f2bf((a1.y * es + vadd) * 0.0625f);
    o1.z = f2bf((a1.z * es + vadd) * 0.0625f); o1.w = f2bf((a1.w * es + vadd) * 0.0625f);
    *reinterpret_cast<ushort4*>(&kvTb[((size_t)bh * 32 + d) * 256 + m0]) = o0;
    *reinterpret_cast<ushort4*>(&kvTb[((size_t)bh * 32 + d) * 256 + m0 + 4]) = o1;
    if (dq == 0) {
        float S = 0.f;
#pragma unroll
        for (int p = 0; p < KV_P; p++) S += kvp[base0 + p * PSZ + 8192 + t];
        ksumf[bh * 256 + t] = (S * es + 1e-4f * (float)N) * 0.0625f;
    }
}

// ---------------- q-side fused attention ----------------
#define ATT_TILES 8
__global__ __launch_bounds__(256) void attn_kernel(const unsigned short* __restrict__ qkv16,
                                                   const unsigned short* __restrict__ projbf,
                                                   const unsigned short* __restrict__ kvTb,
                                                   const float* __restrict__ ksumf,
                                                   unsigned short* __restrict__ attn16) {
    __shared__ __align__(16) unsigned short qp_s[64 * 256];   // 32 KB, swizzled
    int t = threadIdx.x;
    int l = t & 63, w = t >> 6;
    int lr = l & 15, lg = l >> 4;
    int bh = blockIdx.x, b = bh >> 3, h = bh & 7;
    int swz = (lr & 7) << 3;
    int row = w * 16 + lr;

    const unsigned short* kvb = kvTb + (size_t)bh * 32 * 256;
    short8 kva0[8], kva1[8];
#pragma unroll
    for (int k0 = 0; k0 < 8; k0++) {
        kva0[k0] = *reinterpret_cast<const short8*>(kvb + (size_t)lr * 256 + k0 * 32 + lg * 8);
        kva1[k0] = *reinterpret_cast<const short8*>(kvb + (size_t)(16 + lr) * 256 + k0 * 32 + lg * 8);
    }

    int tile0 = blockIdx.y * ATT_TILES;
    size_t qstep = (size_t)64 * 768;
    size_t qbase = ((size_t)(b * N) + tile0 * 64 + w * 16 + lr) * 768 + h * 32 + lg * 8;
    short8 qf = *reinterpret_cast<const short8*>(qkv16 + qbase);

    for (int tl = 0; tl < ATT_TILES; tl++) {
        short8 qfn = qf;
        if (tl < ATT_TILES - 1)
            qfn = *reinterpret_cast<const short8*>(qkv16 + qbase + (size_t)(tl + 1) * qstep);

        float sq = 0.f;
#pragma unroll
        for (int e = 0; e < 8; e++) {
            float xx = bfu2f((unsigned short)qf[e]);
            sq += xx * xx;
        }
        sq += __shfl_xor(sq, 16);
        sq += __shfl_xor(sq, 32);
        float dg = 0.5f * sq;

        f32x4 ua[16];
#pragma unroll
        for (int f = 0; f < 16; f++) {
            short8 bq = *reinterpret_cast<const short8*>(projbf + (f * 16 + lr) * 32 + lg * 8);
            ua[f] = __builtin_amdgcn_mfma_f32_16x16x32_bf16(bq, qf, (f32x4){0.f, 0.f, 0.f, 0.f}, 0, 0, 0);
        }

        float mx = -1e30f;
#pragma unroll
        for (int f = 0; f < 16; f++)
#pragma unroll
            for (int r = 0; r < 4; r++) mx = fmaxf(mx, ua[f][r]);
        mx = fmaxf(mx, __shfl_xor(mx, 16));
        mx = fmaxf(mx, __shfl_xor(mx, 32));

        float zs = 0.f;
#pragma unroll
        for (int f = 0; f < 16; f++) {
            float4 ks4 = *reinterpret_cast<const float4*>(&ksumf[bh * 256 + f * 16 + lg * 4]);
            float p0 = (__expf(ua[f][0] - dg - mx) + 1e-4f) * 0.0625f;
            float p1 = (__expf(ua[f][1] - dg - mx) + 1e-4f) * 0.0625f;
            float p2 = (__expf(ua[f][2] - dg - mx) + 1e-4f) * 0.0625f;
            float p3 = (__expf(ua[f][3] - dg - mx) + 1e-4f) * 0.0625f;
            zs += p0 * ks4.x + p1 * ks4.y + p2 * ks4.z + p3 * ks4.w;
            short4 o;
            o.x = (short)f2bf(p0); o.y = (short)f2bf(p1);
            o.z = (short)f2bf(p2); o.w = (short)f2bf(p3);
            *reinterpret_cast<short4*>(&qp_s[row * 256 + ((f * 16 + lg * 4) ^ swz)]) = o;
        }
        zs += __shfl_xor(zs, 16);
        zs += __shfl_xor(zs, 32);
        float zf = 1.0f / (zs + 1e-6f);

        f32x4 oacc[2];
        oacc[0] = (f32x4){0.f, 0.f, 0.f, 0.f};
        oacc[1] = (f32x4){0.f, 0.f, 0.f, 0.f};
#pragma unroll
        for (int k0 = 0; k0 < 8; k0++) {
            short8 qpf = *reinterpret_cast<const short8*>(
                &qp_s[row * 256 + ((k0 * 32 + lg * 8) ^ swz)]);
            oacc[0] = __builtin_amdgcn_mfma_f32_16x16x32_bf16(kva0[k0], qpf, oacc[0], 0, 0, 0);
            oacc[1] = __builtin_amdgcn_mfma_f32_16x16x32_bf16(kva1[k0], qpf, oacc[1], 0, 0, 0);
        }
        size_t orow = ((size_t)(b * N) + (tile0 + tl) * 64 + w * 16 + lr) * 256 + h * 32;
#pragma unroll
        for (int dd = 0; dd < 2; dd++) {
            short4 o;
            o.x = (short)f2bf(oacc[dd][0] * zf);
            o.y = (short)f2bf(oacc[dd][1] * zf);
            o.z = (short)f2bf(oacc[dd][2] * zf);
            o.w = (short)f2bf(oacc[dd][3] * zf);
            *reinterpret_cast<short4*>(&attn16[orow + dd * 16 + lg * 4]) = o;
        }
        qf = qfn;
    }
}

extern "C" void kernel_launch(void* const* d_in, const int* in_sizes, int n_in,
                              void* d_out, int out_size, void* d_ws, size_t ws_size,
                              hipStream_t stream) {
    const float* x = (const float*)d_in[0];
    const float* pos = (const float*)d_in[1];
    const float* g1 = (const float*)d_in[2];
    const float* b1 = (const float*)d_in[3];
    const float* g2 = (const float*)d_in[4];
    const float* b2 = (const float*)d_in[5];
    const float* Wqkv = (const float*)d_in[6];
    const float* Wproj = (const float*)d_in[7];
    const float* bproj = (const float*)d_in[8];
    const float* W1 = (const float*)d_in[9];
    const float* b1m = (const float*)d_in[10];
    const float* W2 = (const float*)d_in[11];
    const float* b2m = (const float*)d_in[12];
    const float* projm = (const float*)d_in[13];

    float* h = (float*)d_out;
    char* p = (char*)d_ws;
    auto alloc = [&](size_t bytes) { char* r = p; p += (bytes + 255) & ~(size_t)255; return r; };
    unsigned short* wbf    = (unsigned short*)alloc((size_t)DEPTH * 786432 * 2);
    unsigned short* projb  = (unsigned short*)alloc((size_t)DEPTH * M * DH * 2);
    unsigned short* ln16   = (unsigned short*)alloc((size_t)B * N * D * 2);
    unsigned short* qkv16  = (unsigned short*)alloc((size_t)B * N * HID * 2);  // union w/ hid16
    unsigned short* hid16  = qkv16;   // qkv dead by MLP1
    unsigned short* attn16 = (unsigned short*)alloc((size_t)B * N * D * 2);
    float* kvp             = (float*)alloc((size_t)64 * KV_P * PSZ * 4);
    unsigned short* kvTb   = (unsigned short*)alloc((size_t)64 * 32 * 256 * 2);
    float* ksumf           = (float*)alloc((size_t)64 * 256 * 4);

    for (int l = 0; l < DEPTH; l++) {
        size_t lb = (size_t)l * 786432;
        wtrans_kernel<<<dim3(768 / 32, 256 / 32), 256, 0, stream>>>(
            Wqkv + (size_t)l * D * 3 * D, wbf + lb + 0, 256, 768, 512);
        wtrans_kernel<<<dim3(256 / 32, 256 / 32), 256, 0, stream>>>(
            Wproj + (size_t)l * D * D, wbf + lb + 196608, 256, 256, 0);
        wtrans_kernel<<<dim3(1024 / 32, 256 / 32), 256, 0, stream>>>(
            W1 + (size_t)l * D * HID, wbf + lb + 262144, 256, 1024, 0);
        wtrans_kernel<<<dim3(256 / 32, 1024 / 32), 256, 0, stream>>>(
            W2 + (size_t)l * HID * D, wbf + lb + 524288, 1024, 256, 0);
    }
    projbf_kernel<<<DEPTH * M * DH / 256, 256, 0, stream>>>(projm, projb);

    add_pos_kernel<<<B * N * D / 256, 256, 0, stream>>>(x, pos, h);

    for (int l = 0; l < DEPTH; l++) {
        size_t lb = (size_t)l * 786432;
        const unsigned short* wqT = wbf + lb + 0;
        const unsigned short* wpT = wbf + lb + 196608;
        const unsigned short* w1T = wbf + lb + 262144;
        const unsigned short* w2T = wbf + lb + 524288;
        const float* bp = bproj + (size_t)l * D;
        const float* b1l = b1m + (size_t)l * HID;
        const float* b2l = b2m + (size_t)l * D;
        const unsigned short* prb = projb + (size_t)l * M * DH;

        ln_kernel<<<B * N / 4, 256, 0, stream>>>(h, g1, b1, ln16);
        mgemm_kernel<false, false, false, true><<<dim3(768 / 128, B * N / 256), 256, 0, stream>>>(
            ln16, wqT, nullptr, nullptr, qkv16, 256, 768);
        kv_kernel<<<dim3(B * H, KV_P), 256, 0, stream>>>(qkv16, prb, kvp);
        kv_combine_kernel<<<B * H * 4, 256, 0, stream>>>(kvp, kvTb, ksumf);
        attn_kernel<<<dim3(B * H, (N / 64) / ATT_TILES), 256, 0, stream>>>(
            qkv16, prb, kvTb, ksumf, attn16);
        mgemm_kernel<true, false, true, false><<<dim3(256 / 128, B * N / 256), 256, 0, stream>>>(
            attn16, wpT, bp, h, nullptr, 256, 256);
        ln_kernel<<<B * N / 4, 256, 0, stream>>>(h, g2, b2, ln16);
        mgemm_kernel<true, true, false, true><<<dim3(1024 / 128, B * N / 256), 256, 0, stream>>>(
            ln16, w1T, b1l, nullptr, hid16, 256, 1024);
        mgemm_kernel<true, false, true, false><<<dim3(256 / 128, B * N / 256), 256, 0, stream>>>(
            hid16, w2T, b2l, h, nullptr, 1024, 256);
    }
}

// Round 19
// 882.094 us; speedup vs baseline: 1.1659x; 1.1659x over previous
//
#include <hip/hip_runtime.h>
#include <hip/hip_bf16.h>
#include <math.h>

#define B 8
#define N 4096
#define D 256
#define H 8
#define DH 32
#define M 256
#define DEPTH 4
#define HID 1024
#define NRM 0.4204482076268573f   // 32^-0.25

typedef __attribute__((ext_vector_type(8))) short short8;
typedef __attribute__((ext_vector_type(4))) float f32x4;

static __device__ __forceinline__ unsigned short f2bf(float f) {
    __hip_bfloat16 h = __float2bfloat16(f);
    return __builtin_bit_cast(unsigned short, h);
}
static __device__ __forceinline__ float bfu2f(unsigned short u) {
    unsigned int x = ((unsigned int)u) << 16;
    return __builtin_bit_cast(float, x);
}
static __device__ __forceinline__ float gelu_fast(float x) {
    float z = 0.7978845608028654f * (x + 0.044715f * x * x * x);
    float e = __expf(2.0f * z);
    float th = 1.0f - 2.0f / (e + 1.0f);
    return 0.5f * x * (1.0f + th);
}

// ---------------- h = x + pos ----------------
__global__ void add_pos_kernel(const float* __restrict__ x, const float* __restrict__ pos,
                               float* __restrict__ h) {
    int i = blockIdx.x * 256 + threadIdx.x;
    int nd = i % (N * D);
    h[i] = x[i] + pos[nd];
}

// ---------------- proj fp32 -> bf16 copy ----------------
__global__ void projbf_kernel(const float* __restrict__ in, unsigned short* __restrict__ out) {
    int i = blockIdx.x * 256 + threadIdx.x;     // DEPTH*M*DH elements
    out[i] = f2bf(in[i]);
}

// ---- weight fp32 (K x N) -> bf16 transposed (N x K), cols < slim scaled by NRM ----
// batched over layers via blockIdx.z
__global__ __launch_bounds__(256) void wtrans_kernel(const float* __restrict__ in0,
                                                     unsigned short* __restrict__ out0,
                                                     int Kd, int Nd, int slim,
                                                     size_t in_ls, size_t out_ls) {
    const float* in = in0 + (size_t)blockIdx.z * in_ls;
    unsigned short* out = out0 + (size_t)blockIdx.z * out_ls;
    __shared__ float tl[32][33];
    int n0 = blockIdx.x * 32, k0 = blockIdx.y * 32;
    int t = threadIdx.x;
    int kk = t >> 3, c4 = (t & 7) * 4;
    float4 v = *reinterpret_cast<const float4*>(&in[(size_t)(k0 + kk) * Nd + n0 + c4]);
    tl[kk][c4 + 0] = v.x; tl[kk][c4 + 1] = v.y; tl[kk][c4 + 2] = v.z; tl[kk][c4 + 3] = v.w;
    __syncthreads();
    int nn = t >> 3, k4 = (t & 7) * 4;
    float sc = (n0 + nn < slim) ? NRM : 1.0f;
    ushort4 o;
    o.x = f2bf(tl[k4 + 0][nn] * sc); o.y = f2bf(tl[k4 + 1][nn] * sc);
    o.z = f2bf(tl[k4 + 2][nn] * sc); o.w = f2bf(tl[k4 + 3][nn] * sc);
    *reinterpret_cast<ushort4*>(&out[(size_t)(n0 + nn) * Kd + k0 + k4]) = o;
}

// ---------------- LayerNorm -> bf16 ----------------
__global__ __launch_bounds__(256) void ln_kernel(const float* __restrict__ in,
                                                 const float* __restrict__ g,
                                                 const float* __restrict__ bb,
                                                 unsigned short* __restrict__ out) {
    int wave = threadIdx.x >> 6, lane = threadIdx.x & 63;
    long row = (long)blockIdx.x * 4 + wave;
    float4 v = reinterpret_cast<const float4*>(in + row * D)[lane];
    float s = v.x + v.y + v.z + v.w;
#pragma unroll
    for (int o = 32; o >= 1; o >>= 1) s += __shfl_xor(s, o);
    float mu = s * (1.0f / D);
    float d0 = v.x - mu, d1 = v.y - mu, d2 = v.z - mu, d3 = v.w - mu;
    float ss = d0 * d0 + d1 * d1 + d2 * d2 + d3 * d3;
#pragma unroll
    for (int o = 32; o >= 1; o >>= 1) ss += __shfl_xor(ss, o);
    float inv = rsqrtf(ss * (1.0f / D) + 1e-6f);
    float4 gv = reinterpret_cast<const float4*>(g)[lane];
    float4 bv = reinterpret_cast<const float4*>(bb)[lane];
    ushort4 o4;
    o4.x = f2bf(d0 * inv * gv.x + bv.x);
    o4.y = f2bf(d1 * inv * gv.y + bv.y);
    o4.z = f2bf(d2 * inv * gv.z + bv.z);
    o4.w = f2bf(d3 * inv * gv.w + bv.w);
    *reinterpret_cast<ushort4*>(&out[row * D + lane * 4]) = o4;
}

// ---------------- bf16 MFMA GEMM: out = A(MxK) @ Bt(NxK)^T ----------------
// BK=64, double-buffered, ONE barrier per K-step, compile-time NK (full unroll),
// chunk-XOR swizzle (chunk ^= row&7) on write and read, XCD-swizzled grid,
// operand-swapped MFMA (reg-dim = N), vectorized epilogue.
template <int NK, bool BIAS, bool GELU_ACT, bool RESID, bool OUT16>
__global__ __launch_bounds__(256) void mgemm_kernel(const unsigned short* __restrict__ A,
                                                    const unsigned short* __restrict__ Bt,
                                                    const float* __restrict__ bias,
                                                    float* __restrict__ C,
                                                    unsigned short* __restrict__ O16,
                                                    int Nc) {
    const int K = NK * 64;
    __shared__ __align__(16) short Als[2][128][64];
    __shared__ __align__(16) short Bls[2][128][64];
    int t = threadIdx.x;
    int l = t & 63, w = t >> 6;
    int wr = w >> 1, wc = w & 1;
    int nwg = gridDim.x * gridDim.y;
    int bid = blockIdx.y * gridDim.x + blockIdx.x;
    int lgid = (bid & 7) * (nwg >> 3) + (bid >> 3);
    int bx = lgid % gridDim.x;
    int by = lgid / gridDim.x;
    long m0 = (long)by * 128;
    int n0 = bx * 128;
    int lr = l & 15;
    int lg = l >> 4;
    int srow = t >> 1, half = t & 1;     // staging: row t>>1, 64B half-row

    const unsigned short* Ap = &A[(size_t)(m0 + srow) * K + half * 32];
    const unsigned short* Bp = &Bt[(size_t)(n0 + srow) * K + half * 32];

    short* awp[4];
    short* bwp[4];
    short* awp1[4];
    short* bwp1[4];
#pragma unroll
    for (int i = 0; i < 4; i++) {
        int cw = ((half * 4 + i) ^ (srow & 7)) * 8;
        awp[i] = &Als[0][srow][cw];
        bwp[i] = &Bls[0][srow][cw];
        awp1[i] = &Als[1][srow][cw];
        bwp1[i] = &Bls[1][srow][cw];
    }

    short8 ra[4], rb[4];
#pragma unroll
    for (int i = 0; i < 4; i++) {
        ra[i] = *reinterpret_cast<const short8*>(Ap + i * 8);
        rb[i] = *reinterpret_cast<const short8*>(Bp + i * 8);
    }
#pragma unroll
    for (int i = 0; i < 4; i++) {
        *reinterpret_cast<short8*>(awp[i]) = ra[i];
        *reinterpret_cast<short8*>(bwp[i]) = rb[i];
    }
    if (NK > 1) {
#pragma unroll
        for (int i = 0; i < 4; i++) {
            ra[i] = *reinterpret_cast<const short8*>(Ap + 64 + i * 8);
            rb[i] = *reinterpret_cast<const short8*>(Bp + 64 + i * 8);
        }
    }
    __syncthreads();

    f32x4 acc[4][4];
#pragma unroll
    for (int i = 0; i < 4; i++)
#pragma unroll
        for (int j = 0; j < 4; j++) acc[i][j] = (f32x4){0.f, 0.f, 0.f, 0.f};

#pragma unroll
    for (int it = 0; it < NK; it++) {
        int buf = it & 1;
        short8 a[4][2], b[4][2];
#pragma unroll
        for (int i = 0; i < 4; i++) {
            int row = wr * 64 + i * 16 + lr;
#pragma unroll
            for (int ks = 0; ks < 2; ks++) {
                int cr = ((ks * 4 + lg) ^ (lr & 7)) * 8;
                a[i][ks] = *reinterpret_cast<const short8*>(&Als[buf][row][cr]);
            }
        }
#pragma unroll
        for (int j = 0; j < 4; j++) {
            int row = wc * 64 + j * 16 + lr;
#pragma unroll
            for (int ks = 0; ks < 2; ks++) {
                int cr = ((ks * 4 + lg) ^ (lr & 7)) * 8;
                b[j][ks] = *reinterpret_cast<const short8*>(&Bls[buf][row][cr]);
            }
        }
        if (it + 1 < NK) {
#pragma unroll
            for (int i = 0; i < 4; i++) {
                if (buf == 0) {
                    *reinterpret_cast<short8*>(awp1[i]) = ra[i];
                    *reinterpret_cast<short8*>(bwp1[i]) = rb[i];
                } else {
                    *reinterpret_cast<short8*>(awp[i]) = ra[i];
                    *reinterpret_cast<short8*>(bwp[i]) = rb[i];
                }
            }
            if (it + 2 < NK) {
                int ko = (it + 2) * 64;
#pragma unroll
                for (int i = 0; i < 4; i++) {
                    ra[i] = *reinterpret_cast<const short8*>(Ap + ko + i * 8);
                    rb[i] = *reinterpret_cast<const short8*>(Bp + ko + i * 8);
                }
            }
        }
#pragma unroll
        for (int ks = 0; ks < 2; ks++)
#pragma unroll
            for (int i = 0; i < 4; i++)
#pragma unroll
                for (int j = 0; j < 4; j++)   // swapped: reg-dim = n
                    acc[i][j] = __builtin_amdgcn_mfma_f32_16x16x32_bf16(b[j][ks], a[i][ks],
                                                                       acc[i][j], 0, 0, 0);
        __syncthreads();
    }

    float4 bias4[4];
    if (BIAS) {
#pragma unroll
        for (int j = 0; j < 4; j++)
            bias4[j] = *reinterpret_cast<const float4*>(&bias[n0 + wc * 64 + j * 16 + lg * 4]);
    }
#pragma unroll
    for (int i = 0; i < 4; i++) {
        long grow = m0 + wr * 64 + i * 16 + lr;
#pragma unroll
        for (int j = 0; j < 4; j++) {
            int gcol = n0 + wc * 64 + j * 16 + lg * 4;
            f32x4 v = acc[i][j];
            if (BIAS) {
                v[0] += bias4[j].x; v[1] += bias4[j].y; v[2] += bias4[j].z; v[3] += bias4[j].w;
            }
            if (GELU_ACT) {
#pragma unroll
                for (int r = 0; r < 4; r++) v[r] = gelu_fast(v[r]);
            }
            if (OUT16) {
                short4 o;
                o.x = (short)f2bf(v[0]); o.y = (short)f2bf(v[1]);
                o.z = (short)f2bf(v[2]); o.w = (short)f2bf(v[3]);
                *reinterpret_cast<short4*>(&O16[grow * Nc + gcol]) = o;
            } else if (RESID) {
                float4 c0 = *reinterpret_cast<const float4*>(&C[grow * Nc + gcol]);
                c0.x += v[0]; c0.y += v[1]; c0.z += v[2]; c0.w += v[3];
                *reinterpret_cast<float4*>(&C[grow * Nc + gcol]) = c0;
            } else {
                float4 c0 = {v[0], v[1], v[2], v[3]};
                *reinterpret_cast<float4*>(&C[grow * Nc + gcol]) = c0;
            }
        }
    }
}

// ---------------- kv: unshifted exp accumulation, partials [d][m] ----------------
#define KV_P 16
#define KV_ROWS (N / KV_P)      // 256
#define PSZ 8484                // 8192 acc[d][m] + 256 asum + 32 vsum + 1 Lm + pad
__global__ __launch_bounds__(256) void kv_kernel(const unsigned short* __restrict__ qkv16,
                                                 const unsigned short* __restrict__ projbf,
                                                 float* __restrict__ kvp) {
    __shared__ __align__(16) unsigned short kp_s[256][64];    // 32 KB, XOR-swz
    __shared__ __align__(16) unsigned short vT_s[32][66];
    __shared__ float red[4];
    __shared__ float asumred[4][256];
    __shared__ float vred[256][4];
    int t = threadIdx.x;
    int l = t & 63, w = t >> 6;
    int lr = l & 15, lg = l >> 4;
    int bh = blockIdx.x, b = bh >> 3, h = bh & 7;
    int n0 = blockIdx.y * KV_ROWS;
    int rsw = (lr & 7) << 3;

    f32x4 kvacc[4][2];
#pragma unroll
    for (int mf = 0; mf < 4; mf++)
#pragma unroll
        for (int dd = 0; dd < 2; dd++) kvacc[mf][dd] = (f32x4){0.f, 0.f, 0.f, 0.f};
    float asum_p[16];
#pragma unroll
    for (int f = 0; f < 16; f++) asum_p[f] = 0.f;
    float4 vs4 = {0.f, 0.f, 0.f, 0.f};
    float cmax = -1e30f;

    for (int c = 0; c < KV_ROWS / 64; c++) {
        __syncthreads();
        size_t kbase = ((size_t)(b * N) + n0 + c * 64 + w * 16 + lr) * 768 + 256 + h * 32 + lg * 8;
        short8 aq = *reinterpret_cast<const short8*>(qkv16 + kbase);
        float sq = 0.f;
#pragma unroll
        for (int e = 0; e < 8; e++) {
            float xx = bfu2f((unsigned short)aq[e]);
            sq += xx * xx;
        }
        sq += __shfl_xor(sq, 16);
        sq += __shfl_xor(sq, 32);
        float dgr[4];
#pragma unroll
        for (int r = 0; r < 4; r++) dgr[r] = 0.5f * __shfl(sq, lg * 4 + r);
        int cbase = (w * 16 + lg * 4) ^ rsw;
#pragma unroll
        for (int f = 0; f < 16; f++) {
            short8 bq = *reinterpret_cast<const short8*>(projbf + (f * 16 + lr) * 32 + lg * 8);
            f32x4 u = __builtin_amdgcn_mfma_f32_16x16x32_bf16(aq, bq, (f32x4){0.f, 0.f, 0.f, 0.f}, 0, 0, 0);
            cmax = fmaxf(cmax, fmaxf(fmaxf(u[0], u[1]), fmaxf(u[2], u[3])));
            float p0 = __expf(u[0] - dgr[0]);
            float p1 = __expf(u[1] - dgr[1]);
            float p2 = __expf(u[2] - dgr[2]);
            float p3 = __expf(u[3] - dgr[3]);
            asum_p[f] += p0 + p1 + p2 + p3;
            short4 o;
            o.x = (short)f2bf(p0); o.y = (short)f2bf(p1);
            o.z = (short)f2bf(p2); o.w = (short)f2bf(p3);
            *reinterpret_cast<short4*>(&kp_s[f * 16 + lr][cbase]) = o;
        }
#pragma unroll
        for (int ii = 0; ii < 2; ii++) {
            int idx = t + ii * 256;
            int nn = idx >> 3, dz = (idx & 7) * 4;
            const unsigned short* vp =
                qkv16 + ((size_t)(b * N) + n0 + c * 64 + nn) * 768 + 512 + h * 32 + dz;
            short4 vv = *reinterpret_cast<const short4*>(vp);
            float v0 = bfu2f((unsigned short)vv.x), v1 = bfu2f((unsigned short)vv.y);
            float v2 = bfu2f((unsigned short)vv.z), v3 = bfu2f((unsigned short)vv.w);
            vs4.x += v0; vs4.y += v1; vs4.z += v2; vs4.w += v3;
            vT_s[dz + 0][nn] = (unsigned short)vv.x; vT_s[dz + 1][nn] = (unsigned short)vv.y;
            vT_s[dz + 2][nn] = (unsigned short)vv.z; vT_s[dz + 3][nn] = (unsigned short)vv.w;
        }
        __syncthreads();
#pragma unroll
        for (int ks = 0; ks < 2; ks++) {
            short8 bv0 = *reinterpret_cast<const short8*>(&vT_s[lr][ks * 32 + lg * 8]);
            short8 bv1 = *reinterpret_cast<const short8*>(&vT_s[16 + lr][ks * 32 + lg * 8]);
#pragma unroll
            for (int mf = 0; mf < 4; mf++) {
                short8 am = *reinterpret_cast<const short8*>(
                    &kp_s[w * 64 + mf * 16 + lr][(ks * 32 + lg * 8) ^ rsw]);
                kvacc[mf][0] = __builtin_amdgcn_mfma_f32_16x16x32_bf16(am, bv0, kvacc[mf][0], 0, 0, 0);
                kvacc[mf][1] = __builtin_amdgcn_mfma_f32_16x16x32_bf16(am, bv1, kvacc[mf][1], 0, 0, 0);
            }
        }
    }
#pragma unroll
    for (int f = 0; f < 16; f++) {
        asum_p[f] += __shfl_xor(asum_p[f], 16);
        asum_p[f] += __shfl_xor(asum_p[f], 32);
    }
    if (l < 16) {
#pragma unroll
        for (int f = 0; f < 16; f++) asumred[w][f * 16 + l] = asum_p[f];
    }
    vred[t][0] = vs4.x; vred[t][1] = vs4.y; vred[t][2] = vs4.z; vred[t][3] = vs4.w;
#pragma unroll
    for (int o = 1; o < 64; o <<= 1) cmax = fmaxf(cmax, __shfl_xor(cmax, o));
    if (l == 0) red[w] = cmax;
    __syncthreads();
    size_t base = ((size_t)bh * KV_P + blockIdx.y) * PSZ;
#pragma unroll
    for (int mf = 0; mf < 4; mf++)
#pragma unroll
        for (int dd = 0; dd < 2; dd++) {
            int m = w * 64 + mf * 16 + lg * 4;
            int d = dd * 16 + lr;
            float4 o;
            o.x = kvacc[mf][dd][0]; o.y = kvacc[mf][dd][1];
            o.z = kvacc[mf][dd][2]; o.w = kvacc[mf][dd][3];
            *reinterpret_cast<float4*>(&kvp[base + (size_t)d * 256 + m]) = o;
        }
    {
        float s = asumred[0][t] + asumred[1][t] + asumred[2][t] + asumred[3][t];
        kvp[base + 8192 + t] = s;
    }
    if (t < 32) {
        int f4g = t >> 2, cc = t & 3;
        float s = 0.f;
#pragma unroll
        for (int g = 0; g < 32; g++) s += vred[g * 8 + f4g][cc];
        kvp[base + 8448 + t] = s;
    }
    if (t == 0) kvp[base + 8480] = fmaxf(fmaxf(red[0], red[1]), fmaxf(red[2], red[3]));
}

// ---------------- combine partials -> kvT bf16, ksum (grid B*H*4) ----------------
__global__ __launch_bounds__(256) void kv_combine_kernel(const float* __restrict__ kvp,
                                                         unsigned short* __restrict__ kvTb,
                                                         float* __restrict__ ksumf) {
    __shared__ float vst[32];
    int t = threadIdx.x;
    int bh = blockIdx.x >> 2, dq = blockIdx.x & 3;
    size_t base0 = (size_t)bh * KV_P * PSZ;
    float gm = -1e30f;
#pragma unroll
    for (int p = 0; p < KV_P; p++) gm = fmaxf(gm, kvp[base0 + p * PSZ + 8480]);
    if (t < 32) {
        float s = 0.f;
#pragma unroll
        for (int p = 0; p < KV_P; p++) s += kvp[base0 + p * PSZ + 8448 + t];
        vst[t] = s;
    }
    __syncthreads();
    float es = __expf(-gm);
    int d = dq * 8 + (t >> 5);
    int m0 = (t & 31) * 8;
    float4 a0 = {0.f, 0.f, 0.f, 0.f}, a1 = {0.f, 0.f, 0.f, 0.f};
#pragma unroll
    for (int p = 0; p < KV_P; p++) {
        const float* src = &kvp[base0 + p * PSZ + (size_t)d * 256 + m0];
        float4 x0 = *reinterpret_cast<const float4*>(src);
        float4 x1 = *reinterpret_cast<const float4*>(src + 4);
        a0.x += x0.x; a0.y += x0.y; a0.z += x0.z; a0.w += x0.w;
        a1.x += x1.x; a1.y += x1.y; a1.z += x1.z; a1.w += x1.w;
    }
    float vadd = 1e-4f * vst[d];
    ushort4 o0, o1;
    o0.x = f2bf((a0.x * es + vadd) * 0.0625f); o0.y = f2bf((a0.y * es + vadd) * 0.0625f);
    o0.z = f2bf((a0.z * es + vadd) * 0.0625f); o0.w = f2bf((a0.w * es + vadd) * 0.0625f);
    o1.x = f2bf((a1.x * es + vadd) * 0.0625f); o1.y = f2bf((a1.y * es + vadd) * 0.0625f);
    o1.z = f2bf((a1.z * es + vadd) * 0.0625f); o1.w = f2bf((a1.w * es + vadd) * 0.0625f);
    *reinterpret_cast<ushort4*>(&kvTb[((size_t)bh * 32 + d) * 256 + m0]) = o0;
    *reinterpret_cast<ushort4*>(&kvTb[((size_t)bh * 32 + d) * 256 + m0 + 4]) = o1;
    if (dq == 0) {
        float S = 0.f;
#pragma unroll
        for (int p = 0; p < KV_P; p++) S += kvp[base0 + p * PSZ + 8192 + t];
        ksumf[bh * 256 + t] = (S * es + 1e-4f * (float)N) * 0.0625f;
    }
}

// ---------------- q-side fused attention ----------------
#define ATT_TILES 8
__global__ __launch_bounds__(256) void attn_kernel(const unsigned short* __restrict__ qkv16,
                                                   const unsigned short* __restrict__ projbf,
                                                   const unsigned short* __restrict__ kvTb,
                                                   const float* __restrict__ ksumf,
                                                   unsigned short* __restrict__ attn16) {
    __shared__ __align__(16) unsigned short qp_s[64 * 256];   // 32 KB, swizzled
    int t = threadIdx.x;
    int l = t & 63, w = t >> 6;
    int lr = l & 15, lg = l >> 4;
    int bh = blockIdx.x, b = bh >> 3, h = bh & 7;
    int swz = (lr & 7) << 3;
    int row = w * 16 + lr;

    const unsigned short* kvb = kvTb + (size_t)bh * 32 * 256;
    short8 kva0[8], kva1[8];
#pragma unroll
    for (int k0 = 0; k0 < 8; k0++) {
        kva0[k0] = *reinterpret_cast<const short8*>(kvb + (size_t)lr * 256 + k0 * 32 + lg * 8);
        kva1[k0] = *reinterpret_cast<const short8*>(kvb + (size_t)(16 + lr) * 256 + k0 * 32 + lg * 8);
    }

    int tile0 = blockIdx.y * ATT_TILES;
    size_t qstep = (size_t)64 * 768;
    size_t qbase = ((size_t)(b * N) + tile0 * 64 + w * 16 + lr) * 768 + h * 32 + lg * 8;
    short8 qf = *reinterpret_cast<const short8*>(qkv16 + qbase);

    for (int tl = 0; tl < ATT_TILES; tl++) {
        short8 qfn = qf;
        if (tl < ATT_TILES - 1)
            qfn = *reinterpret_cast<const short8*>(qkv16 + qbase + (size_t)(tl + 1) * qstep);

        float sq = 0.f;
#pragma unroll
        for (int e = 0; e < 8; e++) {
            float xx = bfu2f((unsigned short)qf[e]);
            sq += xx * xx;
        }
        sq += __shfl_xor(sq, 16);
        sq += __shfl_xor(sq, 32);
        float dg = 0.5f * sq;

        f32x4 ua[16];
#pragma unroll
        for (int f = 0; f < 16; f++) {
            short8 bq = *reinterpret_cast<const short8*>(projbf + (f * 16 + lr) * 32 + lg * 8);
            ua[f] = __builtin_amdgcn_mfma_f32_16x16x32_bf16(bq, qf, (f32x4){0.f, 0.f, 0.f, 0.f}, 0, 0, 0);
        }

        float mx = -1e30f;
#pragma unroll
        for (int f = 0; f < 16; f++)
#pragma unroll
            for (int r = 0; r < 4; r++) mx = fmaxf(mx, ua[f][r]);
        mx = fmaxf(mx, __shfl_xor(mx, 16));
        mx = fmaxf(mx, __shfl_xor(mx, 32));

        float zs = 0.f;
#pragma unroll
        for (int f = 0; f < 16; f++) {
            float4 ks4 = *reinterpret_cast<const float4*>(&ksumf[bh * 256 + f * 16 + lg * 4]);
            float p0 = (__expf(ua[f][0] - dg - mx) + 1e-4f) * 0.0625f;
            float p1 = (__expf(ua[f][1] - dg - mx) + 1e-4f) * 0.0625f;
            float p2 = (__expf(ua[f][2] - dg - mx) + 1e-4f) * 0.0625f;
            float p3 = (__expf(ua[f][3] - dg - mx) + 1e-4f) * 0.0625f;
            zs += p0 * ks4.x + p1 * ks4.y + p2 * ks4.z + p3 * ks4.w;
            short4 o;
            o.x = (short)f2bf(p0); o.y = (short)f2bf(p1);
            o.z = (short)f2bf(p2); o.w = (short)f2bf(p3);
            *reinterpret_cast<short4*>(&qp_s[row * 256 + ((f * 16 + lg * 4) ^ swz)]) = o;
        }
        zs += __shfl_xor(zs, 16);
        zs += __shfl_xor(zs, 32);
        float zf = 1.0f / (zs + 1e-6f);

        f32x4 oacc[2];
        oacc[0] = (f32x4){0.f, 0.f, 0.f, 0.f};
        oacc[1] = (f32x4){0.f, 0.f, 0.f, 0.f};
#pragma unroll
        for (int k0 = 0; k0 < 8; k0++) {
            short8 qpf = *reinterpret_cast<const short8*>(
                &qp_s[row * 256 + ((k0 * 32 + lg * 8) ^ swz)]);
            oacc[0] = __builtin_amdgcn_mfma_f32_16x16x32_bf16(kva0[k0], qpf, oacc[0], 0, 0, 0);
            oacc[1] = __builtin_amdgcn_mfma_f32_16x16x32_bf16(kva1[k0], qpf, oacc[1], 0, 0, 0);
        }
        size_t orow = ((size_t)(b * N) + (tile0 + tl) * 64 + w * 16 + lr) * 256 + h * 32;
#pragma unroll
        for (int dd = 0; dd < 2; dd++) {
            short4 o;
            o.x = (short)f2bf(oacc[dd][0] * zf);
            o.y = (short)f2bf(oacc[dd][1] * zf);
            o.z = (short)f2bf(oacc[dd][2] * zf);
            o.w = (short)f2bf(oacc[dd][3] * zf);
            *reinterpret_cast<short4*>(&attn16[orow + dd * 16 + lg * 4]) = o;
        }
        qf = qfn;
    }
}

extern "C" void kernel_launch(void* const* d_in, const int* in_sizes, int n_in,
                              void* d_out, int out_size, void* d_ws, size_t ws_size,
                              hipStream_t stream) {
    const float* x = (const float*)d_in[0];
    const float* pos = (const float*)d_in[1];
    const float* g1 = (const float*)d_in[2];
    const float* b1 = (const float*)d_in[3];
    const float* g2 = (const float*)d_in[4];
    const float* b2 = (const float*)d_in[5];
    const float* Wqkv = (const float*)d_in[6];
    const float* Wproj = (const float*)d_in[7];
    const float* bproj = (const float*)d_in[8];
    const float* W1 = (const float*)d_in[9];
    const float* b1m = (const float*)d_in[10];
    const float* W2 = (const float*)d_in[11];
    const float* b2m = (const float*)d_in[12];
    const float* projm = (const float*)d_in[13];

    float* h = (float*)d_out;
    char* p = (char*)d_ws;
    auto alloc = [&](size_t bytes) { char* r = p; p += (bytes + 255) & ~(size_t)255; return r; };
    unsigned short* wbf    = (unsigned short*)alloc((size_t)DEPTH * 786432 * 2);
    unsigned short* projb  = (unsigned short*)alloc((size_t)DEPTH * M * DH * 2);
    unsigned short* ln16   = (unsigned short*)alloc((size_t)B * N * D * 2);
    unsigned short* qkv16  = (unsigned short*)alloc((size_t)B * N * HID * 2);  // union w/ hid16
    unsigned short* hid16  = qkv16;   // qkv dead by MLP1
    unsigned short* attn16 = (unsigned short*)alloc((size_t)B * N * D * 2);
    float* kvp             = (float*)alloc((size_t)64 * KV_P * PSZ * 4);
    unsigned short* kvTb   = (unsigned short*)alloc((size_t)64 * 32 * 256 * 2);
    float* ksumf           = (float*)alloc((size_t)64 * 256 * 4);

    // ---- weight prep, batched over layers (blockIdx.z) ----
    wtrans_kernel<<<dim3(768 / 32, 256 / 32, DEPTH), 256, 0, stream>>>(
        Wqkv, wbf + 0, 256, 768, 512, (size_t)D * 3 * D, 786432);
    wtrans_kernel<<<dim3(256 / 32, 256 / 32, DEPTH), 256, 0, stream>>>(
        Wproj, wbf + 196608, 256, 256, 0, (size_t)D * D, 786432);
    wtrans_kernel<<<dim3(1024 / 32, 256 / 32, DEPTH), 256, 0, stream>>>(
        W1, wbf + 262144, 256, 1024, 0, (size_t)D * HID, 786432);
    wtrans_kernel<<<dim3(256 / 32, 1024 / 32, DEPTH), 256, 0, stream>>>(
        W2, wbf + 524288, 1024, 256, 0, (size_t)HID * D, 786432);
    projbf_kernel<<<DEPTH * M * DH / 256, 256, 0, stream>>>(projm, projb);

    add_pos_kernel<<<B * N * D / 256, 256, 0, stream>>>(x, pos, h);

    for (int l = 0; l < DEPTH; l++) {
        size_t lb = (size_t)l * 786432;
        const unsigned short* wqT = wbf + lb + 0;
        const unsigned short* wpT = wbf + lb + 196608;
        const unsigned short* w1T = wbf + lb + 262144;
        const unsigned short* w2T = wbf + lb + 524288;
        const float* bp = bproj + (size_t)l * D;
        const float* b1l = b1m + (size_t)l * HID;
        const float* b2l = b2m + (size_t)l * D;
        const unsigned short* prb = projb + (size_t)l * M * DH;

        ln_kernel<<<B * N / 4, 256, 0, stream>>>(h, g1, b1, ln16);
        mgemm_kernel<4, false, false, false, true><<<dim3(768 / 128, B * N / 128), 256, 0, stream>>>(
            ln16, wqT, nullptr, nullptr, qkv16, 768);
        kv_kernel<<<dim3(B * H, KV_P), 256, 0, stream>>>(qkv16, prb, kvp);
        kv_combine_kernel<<<B * H * 4, 256, 0, stream>>>(kvp, kvTb, ksumf);
        attn_kernel<<<dim3(B * H, (N / 64) / ATT_TILES), 256, 0, stream>>>(
            qkv16, prb, kvTb, ksumf, attn16);
        mgemm_kernel<4, true, false, true, false><<<dim3(256 / 128, B * N / 128), 256, 0, stream>>>(
            attn16, wpT, bp, h, nullptr, 256);
        ln_kernel<<<B * N / 4, 256, 0, stream>>>(h, g2, b2, ln16);
        mgemm_kernel<4, true, true, false, true><<<dim3(1024 / 128, B * N / 128), 256, 0, stream>>>(
            ln16, w1T, b1l, nullptr, hid16, 1024);
        mgemm_kernel<16, true, false, true, false><<<dim3(256 / 128, B * N / 128), 256, 0, stream>>>(
            hid16, w2T, b2l, h, nullptr, 256);
    }
}